// Round 13
// baseline (248.219 us; speedup 1.0000x reference)
//
#include <hip/hip_runtime.h>
#include <hip/hip_bf16.h>
#include <math.h>

// Problem constants
#define TT 243
#define CC 544            // J*IC
#define NBB 81            // T/BS
#define KK 6
#define HH 8
#define HD 68             // C/H
#define DEPTH 2
#define HID 1088          // 2*C
#define BB 512
#define MTOK 3072         // B*K tokens
#define EPSF 1e-6f

typedef __attribute__((ext_vector_type(8))) short bf16x8;
typedef __attribute__((ext_vector_type(4))) float f32x4;

__device__ __forceinline__ __hip_bfloat16 f2b(float f) { return __float2bfloat16(f); }
__device__ __forceinline__ unsigned short f2bu(float f) {
    __hip_bfloat16 h = __float2bfloat16(f);
    return *(unsigned short*)&h;
}
__device__ __forceinline__ float b2f(unsigned short u) {
    return __uint_as_float(((unsigned)u) << 16);
}

// weight conversion segment ends (float4-index space): qkv | proj | mfc1 | mfc2
#define E0 443904      // 2*1632*544/4
#define E1 591872      // +2*544*544/4
#define E2 887808      // +2*1088*544/4
#define E3 1183744     // +2*544*1088/4

// bw_kernel block ranges
#define RS_BLOCKS 3888            // 3888*32 rows = 124416 = 512*243
#define PS_BLOCKS 8               // 8*32 = 256 >= 243 pos rows
#define WC_BLOCKS 4624            // E3/256
#define BW_GRID (RS_BLOCKS + PS_BLOCKS + WC_BLOCKS)

// ---------------------------------------------------------------------------
// bw_kernel: pure-bandwidth pass (proven R5 version, unchanged)
// ---------------------------------------------------------------------------
__global__ __launch_bounds__(256, 4) void bw_kernel(
    const float* __restrict__ x,     // B*T*C
    const float* __restrict__ pos,   // T*C
    const float* __restrict__ qkvw, const float* __restrict__ projw,
    const float* __restrict__ mfc1w, const float* __restrict__ mfc2w,
    unsigned short* __restrict__ wbf,
    float* __restrict__ L,           // B*T  (x-only)
    float* __restrict__ R,           // B*T  (x-only)
    float* __restrict__ pLR)         // 2*T: pL | pR
{
    const int blk = blockIdx.x;
    const int tid = threadIdx.x;

    if (blk < RS_BLOCKS) {
        const int w = tid >> 6;
        const int lane = tid & 63;
        const int oct = lane & 7;
        const int rsub = lane >> 3;
        const int r = (blk * 4 + w) * 8 + rsub;          // 0..124415
        const float4* xr = (const float4*)x + (size_t)r * 136;
        float4 xs[17];
#pragma unroll
        for (int j = 0; j < 17; ++j) xs[j] = xr[oct + j * 8];
        float aL = 0.0f, aR = 0.0f;
#pragma unroll
        for (int j = 0; j < 17; ++j) {
            const float s = (xs[j].x + xs[j].y) + (xs[j].z + xs[j].w);
            if (j < 8) aL += s;
            else if (j == 8) { if (oct < 4) aL += s; else aR += s; }
            else aR += s;
        }
#pragma unroll
        for (int m = 1; m < 8; m <<= 1) {
            aL += __shfl_xor(aL, m);
            aR += __shfl_xor(aR, m);
        }
        if (oct == 0) { L[r] = aL; R[r] = aR; }
        return;
    }

    if (blk < RS_BLOCKS + PS_BLOCKS) {
        const int w = tid >> 6;
        const int lane = tid & 63;
        const int oct = lane & 7;
        const int rsub = lane >> 3;
        const int r = (blk - RS_BLOCKS) * 32 + w * 8 + rsub;   // 0..255
        const int rc = (r < TT) ? r : (TT - 1);
        const float4* pr = (const float4*)pos + (size_t)rc * 136;
        float4 xs[17];
#pragma unroll
        for (int j = 0; j < 17; ++j) xs[j] = pr[oct + j * 8];
        float aL = 0.0f, aR = 0.0f;
#pragma unroll
        for (int j = 0; j < 17; ++j) {
            const float s = (xs[j].x + xs[j].y) + (xs[j].z + xs[j].w);
            if (j < 8) aL += s;
            else if (j == 8) { if (oct < 4) aL += s; else aR += s; }
            else aR += s;
        }
#pragma unroll
        for (int m = 1; m < 8; m <<= 1) {
            aL += __shfl_xor(aL, m);
            aR += __shfl_xor(aR, m);
        }
        if (oct == 0 && r < TT) { pLR[r] = aL; pLR[TT + r] = aR; }
        return;
    }

    // ---- weight conversion ----
    const int i = (blk - RS_BLOCKS - PS_BLOCKS) * 256 + tid;
    if (i < E3) {
        float4 v;
        if (i < E0)      v = ((const float4*)qkvw)[i];
        else if (i < E1) v = ((const float4*)projw)[i - E0];
        else if (i < E2) v = ((const float4*)mfc1w)[i - E1];
        else             v = ((const float4*)mfc2w)[i - E2];
        ushort4 o;
        o.x = f2bu(v.x); o.y = f2bu(v.y); o.z = f2bu(v.z); o.w = f2bu(v.w);
        ((ushort4*)wbf)[i] = o;
    }
}

// ---------------------------------------------------------------------------
// select: y0, MLP, top-6, gather + fused ln1_0 -> hb (R5, unchanged)
// ---------------------------------------------------------------------------
__global__ __launch_bounds__(128) void select_kernel(
    const float* __restrict__ L, const float* __restrict__ R,
    const float* __restrict__ pLR,
    const float* __restrict__ fc1, const float* __restrict__ fc2,
    const float* __restrict__ x, const float* __restrict__ pos,
    const float* __restrict__ ln1g, const float* __restrict__ ln1b,
    float* __restrict__ t,           // B*6*544 f32
    unsigned short* __restrict__ hb) // B*6*544 bf16 (= ln1_0 output)
{
    const int b = blockIdx.x;
    const int tid = threadIdx.x;
    __shared__ float sf1[NBB * NBB];
    __shared__ float sf2[NBB * NBB];
    __shared__ float sy[NBB], sz[NBB], swv[NBB];
    __shared__ int sidx[KK];
    __shared__ __align__(16) float st[KK][CC];

    const int w = tid >> 6;
    const int lane = tid & 63;
    const float4* x4 = (const float4*)x;
    const float4* p4 = (const float4*)pos;

    for (int i = tid; i < NBB * NBB; i += 128) {
        sf1[i] = fc1[i];
        sf2[i] = fc2[i];
    }

    if (tid < NBB) {
        const int n = tid;
        const float* Lb = L + (size_t)b * TT;
        const float* Rb = R + (size_t)b * TT;
        const float* pL = pLR;
        const float* pR = pLR + TT;
        float s = Lb[3 * n] + Lb[3 * n + 1] + Rb[3 * n] + Rb[3 * n + 1] + Rb[3 * n + 2]
                + pL[3 * n] + pL[3 * n + 1] + pR[3 * n] + pR[3 * n + 1] + pR[3 * n + 2];
        if (n > 0) s += Lb[3 * n - 1] + pL[3 * n - 1];
        sy[n] = s * (1.0f / (3.0f * (float)CC));
    }
    __syncthreads();
    if (tid < NBB) {
        float s = 0.0f;
        for (int j = 0; j < NBB; ++j) s += sf1[tid * NBB + j] * sy[j];
        sz[tid] = fmaxf(s, 0.0f);
    }
    __syncthreads();
    if (tid < NBB) {
        float s = 0.0f;
        for (int j = 0; j < NBB; ++j) s += sf2[tid * NBB + j] * sz[j];
        swv[tid] = 1.0f / (1.0f + expf(-s));
    }
    __syncthreads();
    if (w == 0) {
        float va = (lane < NBB) ? swv[lane] : -1e30f;
        float vb = (lane + 64 < NBB) ? swv[lane + 64] : -1e30f;
        const int ia = lane, ib = lane + 64;
        for (int kk = 0; kk < KK; ++kk) {
            float v = va; int idx = ia;
            if (vb > v) { v = vb; idx = ib; }
#pragma unroll
            for (int m = 1; m < 64; m <<= 1) {
                const float ov = __shfl_xor(v, m);
                const int oi = __shfl_xor(idx, m);
                if (ov > v || (ov == v && oi < idx)) { v = ov; idx = oi; }
            }
            if (lane == 0) sidx[kk] = idx;
            if (ia == idx) va = -1e30f;
            if (ib == idx) vb = -1e30f;
        }
    }
    __syncthreads();

    for (int i = tid; i < KK * 136; i += 128) {
        const int k = i / 136;
        const int c4 = i - k * 136;
        const int n = sidx[k];
        const int shift = (c4 < 68) ? -1 : 0;
        float ax = 0.f, ay = 0.f, az = 0.f, aw = 0.f;
#pragma unroll
        for (int i2 = 0; i2 < 3; ++i2) {
            const int ttr = 3 * n + i2 + shift;
            if (ttr >= 0) {
                const float4 xv = x4[((size_t)b * TT + ttr) * 136 + c4];
                const float4 pv = p4[(size_t)ttr * 136 + c4];
                ax += xv.x + pv.x; ay += xv.y + pv.y; az += xv.z + pv.z; aw += xv.w + pv.w;
            }
        }
        const float inv3 = 1.0f / 3.0f;
        const float4 a = make_float4(ax * inv3, ay * inv3, az * inv3, aw * inv3);
        *(float4*)&st[k][c4 * 4] = a;
        ((float4*)t)[((size_t)b * KK + k) * 136 + c4] = a;
    }
    __syncthreads();

    for (int k = w; k < KK; k += 2) {
        float s = 0.0f, s2 = 0.0f;
        for (int c = lane; c < CC; c += 64) { const float v = st[k][c]; s += v; s2 += v * v; }
#pragma unroll
        for (int off = 32; off; off >>= 1) {
            s += __shfl_xor(s, off);
            s2 += __shfl_xor(s2, off);
        }
        const float m = s / (float)CC;
        const float inv = rsqrtf(s2 / (float)CC - m * m + EPSF);
        for (int c4 = lane; c4 < 136; c4 += 64) {
            const float4 v = *(const float4*)&st[k][c4 * 4];
            const float4 gv = ((const float4*)ln1g)[c4];
            const float4 bv = ((const float4*)ln1b)[c4];
            ushort4 o;
            o.x = f2bu((v.x - m) * inv * gv.x + bv.x);
            o.y = f2bu((v.y - m) * inv * gv.y + bv.y);
            o.z = f2bu((v.z - m) * inv * gv.z + bv.z);
            o.w = f2bu((v.w - m) * inv * gv.w + bv.w);
            ((ushort4*)hb)[((size_t)b * KK + k) * 136 + c4] = o;
        }
    }
}

// ---------------------------------------------------------------------------
// LayerNorm over last dim (544): 4 rows/block, wave per row (R5, unchanged)
// ---------------------------------------------------------------------------
__global__ __launch_bounds__(256) void ln_bf16_kernel(
    const float* __restrict__ X, const float* __restrict__ g,
    const float* __restrict__ bta, unsigned short* __restrict__ Y)
{
    const int row = blockIdx.x * 4 + (threadIdx.x >> 6);
    const int lane = threadIdx.x & 63;
    const float4* xr4 = (const float4*)(X + (size_t)row * CC);
    const float4 v0 = xr4[lane];
    const float4 v1 = xr4[lane + 64];
    float4 v2 = make_float4(0.f, 0.f, 0.f, 0.f);
    if (lane < 8) v2 = xr4[lane + 128];
    float s = (v0.x + v0.y + v0.z + v0.w) + (v1.x + v1.y + v1.z + v1.w)
            + (v2.x + v2.y + v2.z + v2.w);
    float s2 = (v0.x * v0.x + v0.y * v0.y + v0.z * v0.z + v0.w * v0.w)
             + (v1.x * v1.x + v1.y * v1.y + v1.z * v1.z + v1.w * v1.w)
             + (v2.x * v2.x + v2.y * v2.y + v2.z * v2.z + v2.w * v2.w);
#pragma unroll
    for (int off = 32; off; off >>= 1) {
        s += __shfl_xor(s, off);
        s2 += __shfl_xor(s2, off);
    }
    const float m = s / (float)CC;
    const float inv = rsqrtf(s2 / (float)CC - m * m + EPSF);
    ushort4* yr = (ushort4*)(Y + (size_t)row * CC);
    {
        const float4 gv = ((const float4*)g)[lane];
        const float4 bv = ((const float4*)bta)[lane];
        ushort4 o;
        o.x = f2bu((v0.x - m) * inv * gv.x + bv.x);
        o.y = f2bu((v0.y - m) * inv * gv.y + bv.y);
        o.z = f2bu((v0.z - m) * inv * gv.z + bv.z);
        o.w = f2bu((v0.w - m) * inv * gv.w + bv.w);
        yr[lane] = o;
    }
    {
        const float4 gv = ((const float4*)g)[lane + 64];
        const float4 bv = ((const float4*)bta)[lane + 64];
        ushort4 o;
        o.x = f2bu((v1.x - m) * inv * gv.x + bv.x);
        o.y = f2bu((v1.y - m) * inv * gv.y + bv.y);
        o.z = f2bu((v1.z - m) * inv * gv.z + bv.z);
        o.w = f2bu((v1.w - m) * inv * gv.w + bv.w);
        yr[lane + 64] = o;
    }
    if (lane < 8) {
        const float4 gv = ((const float4*)g)[lane + 128];
        const float4 bv = ((const float4*)bta)[lane + 128];
        ushort4 o;
        o.x = f2bu((v2.x - m) * inv * gv.x + bv.x);
        o.y = f2bu((v2.y - m) * inv * gv.y + bv.y);
        o.z = f2bu((v2.z - m) * inv * gv.z + bv.z);
        o.w = f2bu((v2.w - m) * inv * gv.w + bv.w);
        yr[lane + 128] = o;
    }
}

// ---------------------------------------------------------------------------
// bf16 MFMA GEMM, BK=64, 64xBN tile (BN=128 or 64), 4 waves (2x2). (R12)
// ---------------------------------------------------------------------------
template <int BN, int ACT, int RES, int OBF>
__global__ __launch_bounds__(256) void gemm_mfma_kernel(
    const unsigned short* __restrict__ X,   // bf16 M x K
    const unsigned short* __restrict__ W,   // bf16 N x K
    const float* __restrict__ bias,         // N
    const float* __restrict__ Rr,           // M x N (f32) or null
    void* __restrict__ Y,                   // f32 or bf16
    int M, int N, int Kd)
{
    constexpr int NF = BN / 32;        // n-frags per wave: 4 (BN=128) / 2 (BN=64)
    const int bm = blockIdx.y * 64;
    const int bn = blockIdx.x * BN;
    const int tid = threadIdx.x;
    const int K8 = Kd >> 3;    // uint4 per row

    __shared__ __align__(16) short As[64][72];
    __shared__ __align__(16) short Bs[BN][72];

    const int r0 = tid >> 2;           // row 0..63
    const int c0 = tid & 3;            // chunk slot 0..3 (of 8 per 64-k step)
    const int r1 = r0 + 64;            // B rows 64..127 (BN=128 only)

    const uint4* Xu = (const uint4*)X;
    const uint4* Wu = (const uint4*)W;

    const int wid = tid >> 6;
    const int lane = tid & 63;
    const int wm = (wid >> 1) * 32;        // 0 or 32
    const int wn = (wid & 1) * (BN / 2);   // 0 or BN/2
    const int l16 = lane & 15;
    const int l4 = lane >> 4;              // 0..3
    const int koff = l4 * 8;

    f32x4 acc[2][NF] = {};

    const int wr0 = min(bn + r0, N - 1);
    const int wr1 = (BN == 128) ? min(bn + r1, N - 1) : 0;

    const uint4 zz = {0u, 0u, 0u, 0u};
    uint4 a00, a01, b00, b01, b10, b11;
    {
        const int k1 = c0, k2 = c0 + 4;
        a00 = (k1 < K8) ? Xu[(size_t)(bm + r0) * K8 + k1] : zz;
        a01 = (k2 < K8) ? Xu[(size_t)(bm + r0) * K8 + k2] : zz;
        b00 = (k1 < K8) ? Wu[(size_t)wr0 * K8 + k1] : zz;
        b01 = (k2 < K8) ? Wu[(size_t)wr0 * K8 + k2] : zz;
        if constexpr (BN == 128) {
            b10 = (c0 < K8) ? Wu[(size_t)wr1 * K8 + c0] : zz;
            b11 = (c0 + 4 < K8) ? Wu[(size_t)wr1 * K8 + c0 + 4] : zz;
        }
    }

    const int nk = (Kd + 63) >> 6;
    for (int kt = 0; kt < nk; ++kt) {
        __syncthreads();
        *(uint4*)&As[r0][c0 * 8]       = a00;
        *(uint4*)&As[r0][(c0 + 4) * 8] = a01;
        *(uint4*)&Bs[r0][c0 * 8]       = b00;
        *(uint4*)&Bs[r0][(c0 + 4) * 8] = b01;
        if constexpr (BN == 128) {
            *(uint4*)&Bs[r1][c0 * 8]       = b10;
            *(uint4*)&Bs[r1][(c0 + 4) * 8] = b11;
        }
        __syncthreads();

        if (kt + 1 < nk) {
            const int k1 = (kt + 1) * 8 + c0;
            const int k2 = k1 + 4;
            a00 = (k1 < K8) ? Xu[(size_t)(bm + r0) * K8 + k1] : zz;
            a01 = (k2 < K8) ? Xu[(size_t)(bm + r0) * K8 + k2] : zz;
            b00 = (k1 < K8) ? Wu[(size_t)wr0 * K8 + k1] : zz;
            b01 = (k2 < K8) ? Wu[(size_t)wr0 * K8 + k2] : zz;
            if constexpr (BN == 128) {
                b10 = (k1 < K8) ? Wu[(size_t)wr1 * K8 + k1] : zz;
                b11 = (k2 < K8) ? Wu[(size_t)wr1 * K8 + k2] : zz;
            }
        }

#pragma unroll
        for (int kh = 0; kh < 2; ++kh) {
            bf16x8 af[2], bf[NF];
#pragma unroll
            for (int mf = 0; mf < 2; ++mf)
                af[mf] = *(const bf16x8*)&As[wm + mf * 16 + l16][kh * 32 + koff];
#pragma unroll
            for (int nf = 0; nf < NF; ++nf)
                bf[nf] = *(const bf16x8*)&Bs[wn + nf * 16 + l16][kh * 32 + koff];
#pragma unroll
            for (int mf = 0; mf < 2; ++mf)
#pragma unroll
                for (int nf = 0; nf < NF; ++nf)
                    acc[mf][nf] = __builtin_amdgcn_mfma_f32_16x16x32_bf16(af[mf], bf[nf], acc[mf][nf], 0, 0, 0);
        }
    }

    // epilogue
#pragma unroll
    for (int nf = 0; nf < NF; ++nf) {
        const int col = bn + wn + nf * 16 + l16;
        if (col < N) {
            const float bs = bias[col];
#pragma unroll
            for (int mf = 0; mf < 2; ++mf) {
#pragma unroll
                for (int j = 0; j < 4; ++j) {
                    const int row = bm + wm + mf * 16 + l4 * 4 + j;
                    float v = acc[mf][nf][j] + bs;
                    if (ACT == 1) v = 0.5f * v * (1.0f + erff(v * 0.70710678118654752f));
                    if (RES) v += Rr[(size_t)row * N + col];
                    if (OBF) ((unsigned short*)Y)[(size_t)row * N + col] = f2bu(v);
                    else     ((float*)Y)[(size_t)row * N + col] = v;
                }
            }
        }
    }
}

// ---------------------------------------------------------------------------
// Fused attention + proj (+residual): one block handles 2 batches.
// Attention math identical to old attn_kernel (bf16 LDS staging holds the
// same bf16 values). Output rows go to a 16x552 bf16 A-tile (b0: rows 0-5,
// b1: rows 8-13; other rows are don't-care - MFMA C rows are independent).
// proj: 34 n-frags split over 8 waves (static f = w + 8q), BK=32,
// B-fragments streamed directly from L2-resident W.
// ---------------------------------------------------------------------------
__global__ __launch_bounds__(512) void attnproj_kernel(
    const unsigned short* __restrict__ qkv,  // B*6*1632 bf16
    const unsigned short* __restrict__ W,    // 544*544 bf16 (proj, row=out col)
    const float* __restrict__ bias,          // 544
    float* __restrict__ t)                   // B*6*544 f32 (residual in/out)
{
    const int b0 = blockIdx.x * 2;
    const int tid = threadIdx.x;
    const int w = tid >> 6;
    const int lane = tid & 63;

    __shared__ __align__(16) unsigned short sqkv[2][KK * 3 * CC];  // 39168 B
    __shared__ __align__(16) unsigned short aolds[16][552];        // 17664 B
    __shared__ float sp[2][HH][40];                                 // 2560 B

    // stage qkv for both b's (bf16, 1224 uint4 each)
#pragma unroll 2
    for (int bl = 0; bl < 2; ++bl) {
        const uint4* src = (const uint4*)(qkv + (size_t)(b0 + bl) * KK * 3 * CC);
        uint4* dst = (uint4*)sqkv[bl];
        for (int i = tid; i < 1224; i += 512) dst[i] = src[i];
    }
    __syncthreads();

    const float scl = rsqrtf((float)HD);
    const int h = w;   // wave = head

    // scores + softmax (wave h handles head h for both b's)
#pragma unroll 2
    for (int bl = 0; bl < 2; ++bl) {
        if (lane < KK * KK) {
            const int n = lane / KK, m = lane - (lane / KK) * KK;
            const unsigned short* qp = &sqkv[bl][n * (3 * CC) + h * HD];
            const unsigned short* kp = &sqkv[bl][m * (3 * CC) + CC + h * HD];
            float s = 0.0f;
#pragma unroll 4
            for (int d = 0; d < HD; ++d) s += b2f(qp[d]) * b2f(kp[d]);
            sp[bl][h][lane] = s * scl;
        }
    }
    __syncthreads();
#pragma unroll 2
    for (int bl = 0; bl < 2; ++bl) {
        if (lane < KK) {
            const int n = lane;
            float mx = -1e30f;
#pragma unroll
            for (int m = 0; m < KK; ++m) mx = fmaxf(mx, sp[bl][h][n * KK + m]);
            float e[KK];
            float sum = 0.0f;
#pragma unroll
            for (int m = 0; m < KK; ++m) { e[m] = expf(sp[bl][h][n * KK + m] - mx); sum += e[m]; }
            const float inv = 1.0f / sum;
#pragma unroll
            for (int m = 0; m < KK; ++m) sp[bl][h][n * KK + m] = e[m] * inv;
        }
    }
    __syncthreads();

    // P.V -> aolds (b0 rows 0-5, b1 rows 8-13)
    for (int i = tid; i < 2 * KK * CC; i += 512) {
        const int bl = i / (KK * CC);
        const int rem = i - bl * (KK * CC);
        const int n = rem / CC;
        const int cd = rem - n * CC;
        const int hh = cd / HD;
        const int d = cd - hh * HD;
        float acc = 0.0f;
#pragma unroll
        for (int m = 0; m < KK; ++m)
            acc += sp[bl][hh][n * KK + m] * b2f(sqkv[bl][m * (3 * CC) + 2 * CC + hh * HD + d]);
        aolds[bl * 8 + n][cd] = f2bu(acc);
    }
    __syncthreads();

    // proj: wave w owns n-frags f = w, w+8, w+16, w+24, w+32 (f < 34)
    const int l16 = lane & 15;
    const int l4 = lane >> 4;
    f32x4 acc[5] = {};

    for (int kt = 0; kt < 17; ++kt) {
        const int k0 = kt * 32;
        const bf16x8 af = *(const bf16x8*)&aolds[l16][k0 + l4 * 8];
        bf16x8 bfr[5];
#pragma unroll
        for (int q = 0; q < 5; ++q) {
            const int f = w + q * 8;
            if (f < 34) {
                const int n0 = f * 16;
                bfr[q] = *(const bf16x8*)&W[(size_t)(n0 + l16) * CC + k0 + l4 * 8];
            }
        }
#pragma unroll
        for (int q = 0; q < 5; ++q) {
            const int f = w + q * 8;
            if (f < 34)
                acc[q] = __builtin_amdgcn_mfma_f32_16x16x32_bf16(af, bfr[q], acc[q], 0, 0, 0);
        }
    }

    // epilogue: rows 0-5 -> b0 tokens, rows 8-13 -> b1 tokens
#pragma unroll
    for (int q = 0; q < 5; ++q) {
        const int f = w + q * 8;
        if (f < 34) {
            const int col = f * 16 + l16;
            const float bs = bias[col];
#pragma unroll
            for (int j = 0; j < 4; ++j) {
                const int r = l4 * 4 + j;   // 0..15
                const int bl = r >> 3;
                const int n = r & 7;
                if (n < KK) {
                    const size_t idx = ((size_t)(b0 + bl) * KK + n) * CC + col;
                    t[idx] = acc[q][j] + bs + t[idx];
                }
            }
        }
    }
}

// ---------------------------------------------------------------------------
// Final (R5, unchanged): LN(t) with lnf + weighted sum over K
// ---------------------------------------------------------------------------
__global__ __launch_bounds__(256) void final_kernel(
    const float* __restrict__ t, const float* __restrict__ g,
    const float* __restrict__ bta, const float* __restrict__ wm2w,
    const float* __restrict__ wm2b, float* __restrict__ out)
{
    const int b = blockIdx.x;
    const int tid = threadIdx.x;
    __shared__ float st[KK][CC];
    __shared__ float sm[KK], si[KK];
    const float* tb = t + (size_t)b * KK * CC;
    for (int i = tid; i < KK * CC; i += 256) st[i / CC][i % CC] = tb[i];
    __syncthreads();
    const int wid = tid >> 6, lane = tid & 63;
    for (int r = wid; r < KK; r += 4) {
        float s = 0.0f, s2 = 0.0f;
        for (int c = lane; c < CC; c += 64) { const float v = st[r][c]; s += v; s2 += v * v; }
#pragma unroll
        for (int off = 32; off; off >>= 1) { s += __shfl_xor(s, off); s2 += __shfl_xor(s2, off); }
        if (lane == 0) {
            const float m = s / (float)CC;
            sm[r] = m;
            si[r] = rsqrtf(s2 / (float)CC - m * m + EPSF);
        }
    }
    __syncthreads();
    const float w0 = wm2w[0], w1 = wm2w[1], w2 = wm2w[2], w3 = wm2w[3], w4 = wm2w[4], w5 = wm2w[5];
    const float wb = wm2b[0];
    for (int c = tid; c < CC; c += 256) {
        const float gg = g[c], bb = bta[c];
        float acc = wb;
        acc += w0 * ((st[0][c] - sm[0]) * si[0] * gg + bb);
        acc += w1 * ((st[1][c] - sm[1]) * si[1] * gg + bb);
        acc += w2 * ((st[2][c] - sm[2]) * si[2] * gg + bb);
        acc += w3 * ((st[3][c] - sm[3]) * si[3] * gg + bb);
        acc += w4 * ((st[4][c] - sm[4]) * si[4] * gg + bb);
        acc += w5 * ((st[5][c] - sm[5]) * si[5] * gg + bb);
        out[(size_t)b * CC + c] = acc;
    }
}

// ---------------------------------------------------------------------------
extern "C" void kernel_launch(void* const* d_in, const int* in_sizes, int n_in,
                              void* d_out, int out_size, void* d_ws, size_t ws_size,
                              hipStream_t stream)
{
    const float* x      = (const float*)d_in[0];
    const float* pos    = (const float*)d_in[1];
    const float* fc1_w  = (const float*)d_in[2];
    const float* fc2_w  = (const float*)d_in[3];
    const float* ln1_g  = (const float*)d_in[4];
    const float* ln1_b  = (const float*)d_in[5];
    const float* qkv_w  = (const float*)d_in[6];
    const float* qkv_b  = (const float*)d_in[7];
    const float* proj_w = (const float*)d_in[8];
    const float* proj_b = (const float*)d_in[9];
    const float* ln2_g  = (const float*)d_in[10];
    const float* ln2_b  = (const float*)d_in[11];
    const float* mfc1_w = (const float*)d_in[12];
    const float* mfc1_b = (const float*)d_in[13];
    const float* mfc2_w = (const float*)d_in[14];
    const float* mfc2_b = (const float*)d_in[15];
    const float* lnf_g  = (const float*)d_in[16];
    const float* lnf_b  = (const float*)d_in[17];
    const float* wm2_w  = (const float*)d_in[18];
    const float* wm2_b  = (const float*)d_in[19];

    float* ws = (float*)d_ws;
    float* L    = ws;                              // 124416
    float* R    = L + 124416;                      // 124416
    float* pLR  = R + 124416;                      // 486 (+pad)
    float* t    = pLR + 512;                       // 3072*544 f32
    unsigned short* qkvb = (unsigned short*)(t + (size_t)MTOK * CC); // 3072*1632 bf16
    unsigned short* hb  = qkvb + (size_t)MTOK * 3 * CC;              // 3072*544 bf16
    unsigned short* ob  = hb + (size_t)MTOK * CC;                    // (unused)
    unsigned short* gb  = ob + (size_t)MTOK * CC;                    // 3072*1088 bf16
    unsigned short* wbf = gb + (size_t)MTOK * HID;                   // 4,734,976 bf16

    unsigned short* wqkv = wbf;                         // 2 x (1632*544)
    unsigned short* wprj = wbf + 1775616;               // 2 x (544*544)
    unsigned short* wf1  = wbf + 2367488;               // 2 x (1088*544)
    unsigned short* wf2  = wbf + 3551232;               // 2 x (544*1088)

    // pure-BW pass: x row half-sums || pos row half-sums || weight conversion
    bw_kernel<<<BW_GRID, 256, 0, stream>>>(
        x, pos, qkv_w, proj_w, mfc1_w, mfc2_w, wbf, L, R, pLR);

    // selection + gather + fused ln1 (layer 0)
    select_kernel<<<BB, 128, 0, stream>>>(
        L, R, pLR, fc1_w, fc2_w, x, pos, ln1_g, ln1_b, t, hb);

    for (int i = 0; i < DEPTH; ++i) {
        if (i > 0) {
            ln_bf16_kernel<<<MTOK / 4, 256, 0, stream>>>(t, ln1_g + i * CC, ln1_b + i * CC, hb);
        }
        gemm_mfma_kernel<128, 0, 0, 1><<<dim3(13, 48), 256, 0, stream>>>(
            hb, wqkv + (size_t)i * 1632 * 544, qkv_b + (size_t)i * 3 * CC,
            nullptr, qkvb, MTOK, 3 * CC, CC);
        // fused attention + proj (+residual into t)
        attnproj_kernel<<<BB / 2, 512, 0, stream>>>(
            qkvb, wprj + (size_t)i * 544 * 544, proj_b + (size_t)i * CC, t);
        ln_bf16_kernel<<<MTOK / 4, 256, 0, stream>>>(t, ln2_g + i * CC, ln2_b + i * CC, hb);
        gemm_mfma_kernel<128, 1, 0, 1><<<dim3(9, 48), 256, 0, stream>>>(
            hb, wf1 + (size_t)i * HID * 544, mfc1_b + (size_t)i * HID,
            nullptr, gb, MTOK, HID, CC);
        gemm_mfma_kernel<64, 0, 1, 0><<<dim3(9, 48), 256, 0, stream>>>(
            gb, wf2 + (size_t)i * 544 * HID, mfc2_b + (size_t)i * CC,
            t, t, MTOK, CC, HID);
    }

    final_kernel<<<BB, 256, 0, stream>>>(t, lnf_g, lnf_b, wm2_w, wm2_b, (float*)d_out);
}

// Round 14
// 227.611 us; speedup vs baseline: 1.0905x; 1.0905x over previous
//
#include <hip/hip_runtime.h>
#include <hip/hip_bf16.h>
#include <math.h>

// Problem constants
#define TT 243
#define CC 544            // J*IC
#define NBB 81            // T/BS
#define KK 6
#define HH 8
#define HD 68             // C/H
#define DEPTH 2
#define HID 1088          // 2*C
#define BB 512
#define MTOK 3072         // B*K tokens
#define EPSF 1e-6f

typedef __attribute__((ext_vector_type(8))) short bf16x8;
typedef __attribute__((ext_vector_type(4))) float f32x4;

__device__ __forceinline__ __hip_bfloat16 f2b(float f) { return __float2bfloat16(f); }
__device__ __forceinline__ unsigned short f2bu(float f) {
    __hip_bfloat16 h = __float2bfloat16(f);
    return *(unsigned short*)&h;
}
__device__ __forceinline__ float b2f_lo(unsigned int u) { return __uint_as_float(u << 16); }
__device__ __forceinline__ float b2f_hi(unsigned int u) { return __uint_as_float(u & 0xffff0000u); }

// weight conversion segment ends (float4-index space): qkv | proj | mfc1 | mfc2
#define E0 443904      // 2*1632*544/4
#define E1 591872      // +2*544*544/4
#define E2 887808      // +2*1088*544/4
#define E3 1183744     // +2*544*1088/4

// bw_kernel block ranges
#define RS_BLOCKS 3888            // 3888*32 rows = 124416 = 512*243
#define PS_BLOCKS 8               // 8*32 = 256 >= 243 pos rows
#define WC_BLOCKS 4624            // E3/256
#define BW_GRID (RS_BLOCKS + PS_BLOCKS + WC_BLOCKS)

// ---------------------------------------------------------------------------
// bw_kernel: pure-bandwidth pass (proven R5 version, unchanged)
// ---------------------------------------------------------------------------
__global__ __launch_bounds__(256, 4) void bw_kernel(
    const float* __restrict__ x,     // B*T*C
    const float* __restrict__ pos,   // T*C
    const float* __restrict__ qkvw, const float* __restrict__ projw,
    const float* __restrict__ mfc1w, const float* __restrict__ mfc2w,
    unsigned short* __restrict__ wbf,
    float* __restrict__ L,           // B*T  (x-only)
    float* __restrict__ R,           // B*T  (x-only)
    float* __restrict__ pLR)         // 2*T: pL | pR
{
    const int blk = blockIdx.x;
    const int tid = threadIdx.x;

    if (blk < RS_BLOCKS) {
        const int w = tid >> 6;
        const int lane = tid & 63;
        const int oct = lane & 7;
        const int rsub = lane >> 3;
        const int r = (blk * 4 + w) * 8 + rsub;          // 0..124415
        const float4* xr = (const float4*)x + (size_t)r * 136;
        float4 xs[17];
#pragma unroll
        for (int j = 0; j < 17; ++j) xs[j] = xr[oct + j * 8];
        float aL = 0.0f, aR = 0.0f;
#pragma unroll
        for (int j = 0; j < 17; ++j) {
            const float s = (xs[j].x + xs[j].y) + (xs[j].z + xs[j].w);
            if (j < 8) aL += s;
            else if (j == 8) { if (oct < 4) aL += s; else aR += s; }
            else aR += s;
        }
#pragma unroll
        for (int m = 1; m < 8; m <<= 1) {
            aL += __shfl_xor(aL, m);
            aR += __shfl_xor(aR, m);
        }
        if (oct == 0) { L[r] = aL; R[r] = aR; }
        return;
    }

    if (blk < RS_BLOCKS + PS_BLOCKS) {
        const int w = tid >> 6;
        const int lane = tid & 63;
        const int oct = lane & 7;
        const int rsub = lane >> 3;
        const int r = (blk - RS_BLOCKS) * 32 + w * 8 + rsub;   // 0..255
        const int rc = (r < TT) ? r : (TT - 1);
        const float4* pr = (const float4*)pos + (size_t)rc * 136;
        float4 xs[17];
#pragma unroll
        for (int j = 0; j < 17; ++j) xs[j] = pr[oct + j * 8];
        float aL = 0.0f, aR = 0.0f;
#pragma unroll
        for (int j = 0; j < 17; ++j) {
            const float s = (xs[j].x + xs[j].y) + (xs[j].z + xs[j].w);
            if (j < 8) aL += s;
            else if (j == 8) { if (oct < 4) aL += s; else aR += s; }
            else aR += s;
        }
#pragma unroll
        for (int m = 1; m < 8; m <<= 1) {
            aL += __shfl_xor(aL, m);
            aR += __shfl_xor(aR, m);
        }
        if (oct == 0 && r < TT) { pLR[r] = aL; pLR[TT + r] = aR; }
        return;
    }

    // ---- weight conversion ----
    const int i = (blk - RS_BLOCKS - PS_BLOCKS) * 256 + tid;
    if (i < E3) {
        float4 v;
        if (i < E0)      v = ((const float4*)qkvw)[i];
        else if (i < E1) v = ((const float4*)projw)[i - E0];
        else if (i < E2) v = ((const float4*)mfc1w)[i - E1];
        else             v = ((const float4*)mfc2w)[i - E2];
        ushort4 o;
        o.x = f2bu(v.x); o.y = f2bu(v.y); o.z = f2bu(v.z); o.w = f2bu(v.w);
        ((ushort4*)wbf)[i] = o;
    }
}

// ---------------------------------------------------------------------------
// select: y0, MLP, top-6, gather + fused ln1_0 -> hb (R5, unchanged)
// ---------------------------------------------------------------------------
__global__ __launch_bounds__(128) void select_kernel(
    const float* __restrict__ L, const float* __restrict__ R,
    const float* __restrict__ pLR,
    const float* __restrict__ fc1, const float* __restrict__ fc2,
    const float* __restrict__ x, const float* __restrict__ pos,
    const float* __restrict__ ln1g, const float* __restrict__ ln1b,
    float* __restrict__ t,           // B*6*544 f32
    unsigned short* __restrict__ hb) // B*6*544 bf16 (= ln1_0 output)
{
    const int b = blockIdx.x;
    const int tid = threadIdx.x;
    __shared__ float sf1[NBB * NBB];
    __shared__ float sf2[NBB * NBB];
    __shared__ float sy[NBB], sz[NBB], swv[NBB];
    __shared__ int sidx[KK];
    __shared__ __align__(16) float st[KK][CC];

    const int w = tid >> 6;
    const int lane = tid & 63;
    const float4* x4 = (const float4*)x;
    const float4* p4 = (const float4*)pos;

    for (int i = tid; i < NBB * NBB; i += 128) {
        sf1[i] = fc1[i];
        sf2[i] = fc2[i];
    }

    if (tid < NBB) {
        const int n = tid;
        const float* Lb = L + (size_t)b * TT;
        const float* Rb = R + (size_t)b * TT;
        const float* pL = pLR;
        const float* pR = pLR + TT;
        float s = Lb[3 * n] + Lb[3 * n + 1] + Rb[3 * n] + Rb[3 * n + 1] + Rb[3 * n + 2]
                + pL[3 * n] + pL[3 * n + 1] + pR[3 * n] + pR[3 * n + 1] + pR[3 * n + 2];
        if (n > 0) s += Lb[3 * n - 1] + pL[3 * n - 1];
        sy[n] = s * (1.0f / (3.0f * (float)CC));
    }
    __syncthreads();
    if (tid < NBB) {
        float s = 0.0f;
        for (int j = 0; j < NBB; ++j) s += sf1[tid * NBB + j] * sy[j];
        sz[tid] = fmaxf(s, 0.0f);
    }
    __syncthreads();
    if (tid < NBB) {
        float s = 0.0f;
        for (int j = 0; j < NBB; ++j) s += sf2[tid * NBB + j] * sz[j];
        swv[tid] = 1.0f / (1.0f + expf(-s));
    }
    __syncthreads();
    if (w == 0) {
        float va = (lane < NBB) ? swv[lane] : -1e30f;
        float vb = (lane + 64 < NBB) ? swv[lane + 64] : -1e30f;
        const int ia = lane, ib = lane + 64;
        for (int kk = 0; kk < KK; ++kk) {
            float v = va; int idx = ia;
            if (vb > v) { v = vb; idx = ib; }
#pragma unroll
            for (int m = 1; m < 64; m <<= 1) {
                const float ov = __shfl_xor(v, m);
                const int oi = __shfl_xor(idx, m);
                if (ov > v || (ov == v && oi < idx)) { v = ov; idx = oi; }
            }
            if (lane == 0) sidx[kk] = idx;
            if (ia == idx) va = -1e30f;
            if (ib == idx) vb = -1e30f;
        }
    }
    __syncthreads();

    for (int i = tid; i < KK * 136; i += 128) {
        const int k = i / 136;
        const int c4 = i - k * 136;
        const int n = sidx[k];
        const int shift = (c4 < 68) ? -1 : 0;
        float ax = 0.f, ay = 0.f, az = 0.f, aw = 0.f;
#pragma unroll
        for (int i2 = 0; i2 < 3; ++i2) {
            const int ttr = 3 * n + i2 + shift;
            if (ttr >= 0) {
                const float4 xv = x4[((size_t)b * TT + ttr) * 136 + c4];
                const float4 pv = p4[(size_t)ttr * 136 + c4];
                ax += xv.x + pv.x; ay += xv.y + pv.y; az += xv.z + pv.z; aw += xv.w + pv.w;
            }
        }
        const float inv3 = 1.0f / 3.0f;
        const float4 a = make_float4(ax * inv3, ay * inv3, az * inv3, aw * inv3);
        *(float4*)&st[k][c4 * 4] = a;
        ((float4*)t)[((size_t)b * KK + k) * 136 + c4] = a;
    }
    __syncthreads();

    for (int k = w; k < KK; k += 2) {
        float s = 0.0f, s2 = 0.0f;
        for (int c = lane; c < CC; c += 64) { const float v = st[k][c]; s += v; s2 += v * v; }
#pragma unroll
        for (int off = 32; off; off >>= 1) {
            s += __shfl_xor(s, off);
            s2 += __shfl_xor(s2, off);
        }
        const float m = s / (float)CC;
        const float inv = rsqrtf(s2 / (float)CC - m * m + EPSF);
        for (int c4 = lane; c4 < 136; c4 += 64) {
            const float4 v = *(const float4*)&st[k][c4 * 4];
            const float4 gv = ((const float4*)ln1g)[c4];
            const float4 bv = ((const float4*)ln1b)[c4];
            ushort4 o;
            o.x = f2bu((v.x - m) * inv * gv.x + bv.x);
            o.y = f2bu((v.y - m) * inv * gv.y + bv.y);
            o.z = f2bu((v.z - m) * inv * gv.z + bv.z);
            o.w = f2bu((v.w - m) * inv * gv.w + bv.w);
            ((ushort4*)hb)[((size_t)b * KK + k) * 136 + c4] = o;
        }
    }
}

// ---------------------------------------------------------------------------
// LayerNorm over last dim (544): 4 rows/block, wave per row (R5, unchanged)
// ---------------------------------------------------------------------------
__global__ __launch_bounds__(256) void ln_bf16_kernel(
    const float* __restrict__ X, const float* __restrict__ g,
    const float* __restrict__ bta, unsigned short* __restrict__ Y)
{
    const int row = blockIdx.x * 4 + (threadIdx.x >> 6);
    const int lane = threadIdx.x & 63;
    const float4* xr4 = (const float4*)(X + (size_t)row * CC);
    const float4 v0 = xr4[lane];
    const float4 v1 = xr4[lane + 64];
    float4 v2 = make_float4(0.f, 0.f, 0.f, 0.f);
    if (lane < 8) v2 = xr4[lane + 128];
    float s = (v0.x + v0.y + v0.z + v0.w) + (v1.x + v1.y + v1.z + v1.w)
            + (v2.x + v2.y + v2.z + v2.w);
    float s2 = (v0.x * v0.x + v0.y * v0.y + v0.z * v0.z + v0.w * v0.w)
             + (v1.x * v1.x + v1.y * v1.y + v1.z * v1.z + v1.w * v1.w)
             + (v2.x * v2.x + v2.y * v2.y + v2.z * v2.z + v2.w * v2.w);
#pragma unroll
    for (int off = 32; off; off >>= 1) {
        s += __shfl_xor(s, off);
        s2 += __shfl_xor(s2, off);
    }
    const float m = s / (float)CC;
    const float inv = rsqrtf(s2 / (float)CC - m * m + EPSF);
    ushort4* yr = (ushort4*)(Y + (size_t)row * CC);
    {
        const float4 gv = ((const float4*)g)[lane];
        const float4 bv = ((const float4*)bta)[lane];
        ushort4 o;
        o.x = f2bu((v0.x - m) * inv * gv.x + bv.x);
        o.y = f2bu((v0.y - m) * inv * gv.y + bv.y);
        o.z = f2bu((v0.z - m) * inv * gv.z + bv.z);
        o.w = f2bu((v0.w - m) * inv * gv.w + bv.w);
        yr[lane] = o;
    }
    {
        const float4 gv = ((const float4*)g)[lane + 64];
        const float4 bv = ((const float4*)bta)[lane + 64];
        ushort4 o;
        o.x = f2bu((v1.x - m) * inv * gv.x + bv.x);
        o.y = f2bu((v1.y - m) * inv * gv.y + bv.y);
        o.z = f2bu((v1.z - m) * inv * gv.z + bv.z);
        o.w = f2bu((v1.w - m) * inv * gv.w + bv.w);
        yr[lane + 64] = o;
    }
    if (lane < 8) {
        const float4 gv = ((const float4*)g)[lane + 128];
        const float4 bv = ((const float4*)bta)[lane + 128];
        ushort4 o;
        o.x = f2bu((v2.x - m) * inv * gv.x + bv.x);
        o.y = f2bu((v2.y - m) * inv * gv.y + bv.y);
        o.z = f2bu((v2.z - m) * inv * gv.z + bv.z);
        o.w = f2bu((v2.w - m) * inv * gv.w + bv.w);
        yr[lane + 128] = o;
    }
}

// ---------------------------------------------------------------------------
// bf16 MFMA GEMM, BK=64, 64xBN tile (BN=128 or 64), 4 waves (2x2).
// BN=64 doubles grid parallelism for the narrow N=544 GEMMs (proj/mfc2:
// 240 -> 432 blocks). K-tail zero-padded in LDS (no MFMA guards).
// ---------------------------------------------------------------------------
template <int BN, int ACT, int RES, int OBF>
__global__ __launch_bounds__(256) void gemm_mfma_kernel(
    const unsigned short* __restrict__ X,   // bf16 M x K
    const unsigned short* __restrict__ W,   // bf16 N x K
    const float* __restrict__ bias,         // N
    const float* __restrict__ Rr,           // M x N (f32) or null
    void* __restrict__ Y,                   // f32 or bf16
    int M, int N, int Kd)
{
    constexpr int NF = BN / 32;        // n-frags per wave: 4 (BN=128) / 2 (BN=64)
    const int bm = blockIdx.y * 64;
    const int bn = blockIdx.x * BN;
    const int tid = threadIdx.x;
    const int K8 = Kd >> 3;    // uint4 per row

    __shared__ __align__(16) short As[64][72];
    __shared__ __align__(16) short Bs[BN][72];

    const int r0 = tid >> 2;           // row 0..63
    const int c0 = tid & 3;            // chunk slot 0..3 (of 8 per 64-k step)
    const int r1 = r0 + 64;            // B rows 64..127 (BN=128 only)

    const uint4* Xu = (const uint4*)X;
    const uint4* Wu = (const uint4*)W;

    const int wid = tid >> 6;
    const int lane = tid & 63;
    const int wm = (wid >> 1) * 32;        // 0 or 32
    const int wn = (wid & 1) * (BN / 2);   // 0 or BN/2
    const int l16 = lane & 15;
    const int l4 = lane >> 4;              // 0..3
    const int koff = l4 * 8;

    f32x4 acc[2][NF] = {};

    const int wr0 = min(bn + r0, N - 1);
    const int wr1 = (BN == 128) ? min(bn + r1, N - 1) : 0;

    const uint4 zz = {0u, 0u, 0u, 0u};
    uint4 a00, a01, b00, b01, b10, b11;
    {
        const int k1 = c0, k2 = c0 + 4;
        a00 = (k1 < K8) ? Xu[(size_t)(bm + r0) * K8 + k1] : zz;
        a01 = (k2 < K8) ? Xu[(size_t)(bm + r0) * K8 + k2] : zz;
        b00 = (k1 < K8) ? Wu[(size_t)wr0 * K8 + k1] : zz;
        b01 = (k2 < K8) ? Wu[(size_t)wr0 * K8 + k2] : zz;
        if constexpr (BN == 128) {
            b10 = (c0 < K8) ? Wu[(size_t)wr1 * K8 + c0] : zz;
            b11 = (c0 + 4 < K8) ? Wu[(size_t)wr1 * K8 + c0 + 4] : zz;
        }
    }

    const int nk = (Kd + 63) >> 6;
    for (int kt = 0; kt < nk; ++kt) {
        __syncthreads();
        *(uint4*)&As[r0][c0 * 8]       = a00;
        *(uint4*)&As[r0][(c0 + 4) * 8] = a01;
        *(uint4*)&Bs[r0][c0 * 8]       = b00;
        *(uint4*)&Bs[r0][(c0 + 4) * 8] = b01;
        if constexpr (BN == 128) {
            *(uint4*)&Bs[r1][c0 * 8]       = b10;
            *(uint4*)&Bs[r1][(c0 + 4) * 8] = b11;
        }
        __syncthreads();

        if (kt + 1 < nk) {
            const int k1 = (kt + 1) * 8 + c0;
            const int k2 = k1 + 4;
            a00 = (k1 < K8) ? Xu[(size_t)(bm + r0) * K8 + k1] : zz;
            a01 = (k2 < K8) ? Xu[(size_t)(bm + r0) * K8 + k2] : zz;
            b00 = (k1 < K8) ? Wu[(size_t)wr0 * K8 + k1] : zz;
            b01 = (k2 < K8) ? Wu[(size_t)wr0 * K8 + k2] : zz;
            if constexpr (BN == 128) {
                b10 = (k1 < K8) ? Wu[(size_t)wr1 * K8 + k1] : zz;
                b11 = (k2 < K8) ? Wu[(size_t)wr1 * K8 + k2] : zz;
            }
        }

#pragma unroll
        for (int kh = 0; kh < 2; ++kh) {
            bf16x8 af[2], bf[NF];
#pragma unroll
            for (int mf = 0; mf < 2; ++mf)
                af[mf] = *(const bf16x8*)&As[wm + mf * 16 + l16][kh * 32 + koff];
#pragma unroll
            for (int nf = 0; nf < NF; ++nf)
                bf[nf] = *(const bf16x8*)&Bs[wn + nf * 16 + l16][kh * 32 + koff];
#pragma unroll
            for (int mf = 0; mf < 2; ++mf)
#pragma unroll
                for (int nf = 0; nf < NF; ++nf)
                    acc[mf][nf] = __builtin_amdgcn_mfma_f32_16x16x32_bf16(af[mf], bf[nf], acc[mf][nf], 0, 0, 0);
        }
    }

    // epilogue
#pragma unroll
    for (int nf = 0; nf < NF; ++nf) {
        const int col = bn + wn + nf * 16 + l16;
        if (col < N) {
            const float bs = bias[col];
#pragma unroll
            for (int mf = 0; mf < 2; ++mf) {
#pragma unroll
                for (int j = 0; j < 4; ++j) {
                    const int row = bm + wm + mf * 16 + l4 * 4 + j;
                    float v = acc[mf][nf][j] + bs;
                    if (ACT == 1) v = 0.5f * v * (1.0f + erff(v * 0.70710678118654752f));
                    if (RES) v += Rr[(size_t)row * N + col];
                    if (OBF) ((unsigned short*)Y)[(size_t)row * N + col] = f2bu(v);
                    else     ((float*)Y)[(size_t)row * N + col] = v;
                }
            }
        }
    }
}

// ---------------------------------------------------------------------------
// Attention (R5, unchanged): per block b; 8 waves = 8 heads
// ---------------------------------------------------------------------------
__global__ __launch_bounds__(512) void attn_kernel(
    const unsigned short* __restrict__ qkv,  // B*6*1632 bf16
    __hip_bfloat16* __restrict__ o)          // B*6*544 bf16
{
    const int b = blockIdx.x;
    __shared__ __align__(16) float sq[KK * 3 * CC];
    __shared__ float sp[HH][40];
    const int tid = threadIdx.x;

    const uint4* src4 = (const uint4*)(qkv + (size_t)b * KK * 3 * CC);  // 1224 uint4
    for (int i = tid; i < (KK * 3 * CC) / 8; i += 512) {
        const uint4 u = src4[i];
        float4 f0, f1;
        f0.x = b2f_lo(u.x); f0.y = b2f_hi(u.x);
        f0.z = b2f_lo(u.y); f0.w = b2f_hi(u.y);
        f1.x = b2f_lo(u.z); f1.y = b2f_hi(u.z);
        f1.z = b2f_lo(u.w); f1.w = b2f_hi(u.w);
        ((float4*)sq)[2 * i] = f0;
        ((float4*)sq)[2 * i + 1] = f1;
    }
    __syncthreads();

    const int h = tid >> 6;
    const int lane = tid & 63;
    const float scl = rsqrtf((float)HD);

    if (lane < KK * KK) {
        const int n = lane / KK, m = lane - (lane / KK) * KK;
        const float* qp = &sq[n * (3 * CC) + 0 * CC + h * HD];
        const float* kp = &sq[m * (3 * CC) + 1 * CC + h * HD];
        float s = 0.0f;
#pragma unroll 4
        for (int d = 0; d < HD; ++d) s += qp[d] * kp[d];
        sp[h][lane] = s * scl;
    }
    __syncthreads();
    if (lane < KK) {
        const int n = lane;
        float mx = -1e30f;
#pragma unroll
        for (int m = 0; m < KK; ++m) mx = fmaxf(mx, sp[h][n * KK + m]);
        float e[KK];
        float sum = 0.0f;
#pragma unroll
        for (int m = 0; m < KK; ++m) { e[m] = expf(sp[h][n * KK + m] - mx); sum += e[m]; }
        const float inv = 1.0f / sum;
#pragma unroll
        for (int m = 0; m < KK; ++m) sp[h][n * KK + m] = e[m] * inv;
    }
    __syncthreads();
    for (int i = tid; i < KK * CC; i += 512) {
        const int n = i / CC;
        const int cd = i - n * CC;
        const int hh = cd / HD;
        const int d = cd - hh * HD;
        float acc = 0.0f;
#pragma unroll
        for (int m = 0; m < KK; ++m)
            acc += sp[hh][n * KK + m] * sq[m * (3 * CC) + 2 * CC + hh * HD + d];
        o[(size_t)b * KK * CC + i] = f2b(acc);
    }
}

// ---------------------------------------------------------------------------
// Final (R5, unchanged): LN(t) with lnf + weighted sum over K
// ---------------------------------------------------------------------------
__global__ __launch_bounds__(256) void final_kernel(
    const float* __restrict__ t, const float* __restrict__ g,
    const float* __restrict__ bta, const float* __restrict__ wm2w,
    const float* __restrict__ wm2b, float* __restrict__ out)
{
    const int b = blockIdx.x;
    const int tid = threadIdx.x;
    __shared__ float st[KK][CC];
    __shared__ float sm[KK], si[KK];
    const float* tb = t + (size_t)b * KK * CC;
    for (int i = tid; i < KK * CC; i += 256) st[i / CC][i % CC] = tb[i];
    __syncthreads();
    const int wid = tid >> 6, lane = tid & 63;
    for (int r = wid; r < KK; r += 4) {
        float s = 0.0f, s2 = 0.0f;
        for (int c = lane; c < CC; c += 64) { const float v = st[r][c]; s += v; s2 += v * v; }
#pragma unroll
        for (int off = 32; off; off >>= 1) { s += __shfl_xor(s, off); s2 += __shfl_xor(s2, off); }
        if (lane == 0) {
            const float m = s / (float)CC;
            sm[r] = m;
            si[r] = rsqrtf(s2 / (float)CC - m * m + EPSF);
        }
    }
    __syncthreads();
    const float w0 = wm2w[0], w1 = wm2w[1], w2 = wm2w[2], w3 = wm2w[3], w4 = wm2w[4], w5 = wm2w[5];
    const float wb = wm2b[0];
    for (int c = tid; c < CC; c += 256) {
        const float gg = g[c], bb = bta[c];
        float acc = wb;
        acc += w0 * ((st[0][c] - sm[0]) * si[0] * gg + bb);
        acc += w1 * ((st[1][c] - sm[1]) * si[1] * gg + bb);
        acc += w2 * ((st[2][c] - sm[2]) * si[2] * gg + bb);
        acc += w3 * ((st[3][c] - sm[3]) * si[3] * gg + bb);
        acc += w4 * ((st[4][c] - sm[4]) * si[4] * gg + bb);
        acc += w5 * ((st[5][c] - sm[5]) * si[5] * gg + bb);
        out[(size_t)b * CC + c] = acc;
    }
}

// ---------------------------------------------------------------------------
extern "C" void kernel_launch(void* const* d_in, const int* in_sizes, int n_in,
                              void* d_out, int out_size, void* d_ws, size_t ws_size,
                              hipStream_t stream)
{
    const float* x      = (const float*)d_in[0];
    const float* pos    = (const float*)d_in[1];
    const float* fc1_w  = (const float*)d_in[2];
    const float* fc2_w  = (const float*)d_in[3];
    const float* ln1_g  = (const float*)d_in[4];
    const float* ln1_b  = (const float*)d_in[5];
    const float* qkv_w  = (const float*)d_in[6];
    const float* qkv_b  = (const float*)d_in[7];
    const float* proj_w = (const float*)d_in[8];
    const float* proj_b = (const float*)d_in[9];
    const float* ln2_g  = (const float*)d_in[10];
    const float* ln2_b  = (const float*)d_in[11];
    const float* mfc1_w = (const float*)d_in[12];
    const float* mfc1_b = (const float*)d_in[13];
    const float* mfc2_w = (const float*)d_in[14];
    const float* mfc2_b = (const float*)d_in[15];
    const float* lnf_g  = (const float*)d_in[16];
    const float* lnf_b  = (const float*)d_in[17];
    const float* wm2_w  = (const float*)d_in[18];
    const float* wm2_b  = (const float*)d_in[19];

    float* ws = (float*)d_ws;
    float* L    = ws;                              // 124416
    float* R    = L + 124416;                      // 124416
    float* pLR  = R + 124416;                      // 486 (+pad)
    float* t    = pLR + 512;                       // 3072*544 f32
    unsigned short* qkvb = (unsigned short*)(t + (size_t)MTOK * CC); // 3072*1632 bf16
    unsigned short* hb  = qkvb + (size_t)MTOK * 3 * CC;              // 3072*544 bf16
    unsigned short* ob  = hb + (size_t)MTOK * CC;                    // 3072*544 bf16
    unsigned short* gb  = ob + (size_t)MTOK * CC;                    // 3072*1088 bf16
    unsigned short* wbf = gb + (size_t)MTOK * HID;                   // 4,734,976 bf16

    unsigned short* wqkv = wbf;                         // 2 x (1632*544)
    unsigned short* wprj = wbf + 1775616;               // 2 x (544*544)
    unsigned short* wf1  = wbf + 2367488;               // 2 x (1088*544)
    unsigned short* wf2  = wbf + 3551232;               // 2 x (544*1088)

    // pure-BW pass: x row half-sums || pos row half-sums || weight conversion
    bw_kernel<<<BW_GRID, 256, 0, stream>>>(
        x, pos, qkv_w, proj_w, mfc1_w, mfc2_w, wbf, L, R, pLR);

    // selection + gather + fused ln1 (layer 0)
    select_kernel<<<BB, 128, 0, stream>>>(
        L, R, pLR, fc1_w, fc2_w, x, pos, ln1_g, ln1_b, t, hb);

    for (int i = 0; i < DEPTH; ++i) {
        if (i > 0) {
            ln_bf16_kernel<<<MTOK / 4, 256, 0, stream>>>(t, ln1_g + i * CC, ln1_b + i * CC, hb);
        }
        gemm_mfma_kernel<128, 0, 0, 1><<<dim3(13, 48), 256, 0, stream>>>(
            hb, wqkv + (size_t)i * 1632 * 544, qkv_b + (size_t)i * 3 * CC,
            nullptr, qkvb, MTOK, 3 * CC, CC);
        attn_kernel<<<BB, 512, 0, stream>>>(qkvb, (__hip_bfloat16*)ob);
        gemm_mfma_kernel<64, 0, 1, 0><<<dim3(9, 48), 256, 0, stream>>>(
            ob, wprj + (size_t)i * 544 * 544, proj_b + (size_t)i * CC,
            t, t, MTOK, CC, CC);
        ln_bf16_kernel<<<MTOK / 4, 256, 0, stream>>>(t, ln2_g + i * CC, ln2_b + i * CC, hb);
        gemm_mfma_kernel<128, 1, 0, 1><<<dim3(9, 48), 256, 0, stream>>>(
            hb, wf1 + (size_t)i * HID * 544, mfc1_b + (size_t)i * HID,
            nullptr, gb, MTOK, HID, CC);
        gemm_mfma_kernel<64, 0, 1, 0><<<dim3(9, 48), 256, 0, stream>>>(
            gb, wf2 + (size_t)i * 544 * HID, mfc2_b + (size_t)i * CC,
            t, t, MTOK, CC, HID);
    }

    final_kernel<<<BB, 256, 0, stream>>>(t, lnf_g, lnf_b, wm2_w, wm2_b, (float*)d_out);
}